// Round 11
// baseline (279.440 us; speedup 1.0000x reference)
//
#include <hip/hip_runtime.h>

typedef _Float16 half2v __attribute__((ext_vector_type(2)));
typedef _Float16 half4v __attribute__((ext_vector_type(4)));
typedef _Float16 half8v __attribute__((ext_vector_type(8)));

#define HH 1024
#define OHW 256
#define TH 16
#define TW 64
#define NR 80        // input-tile rows
#define NCH 34       // data chunks (8 halves) per row = 272 cols
#define TCHP 36      // padded chunks per row
#define ROWH (TCHP*8) // 288 halves per row
#define NTHREADS 256
#define ESPAN 528
#define ECHUNK (ESPAN/4)

#if defined(__has_builtin)
#  if __has_builtin(__builtin_amdgcn_fdot2)
#    define HAS_FDOT2 1
#  endif
#endif
#ifndef HAS_FDOT2
#  define HAS_FDOT2 0
#endif

__constant__ float DEC12c[12] = {
  -1.20162964e-04f,  1.615524292e-03f, -1.0385513306e-02f,  4.3619155884e-02f,
  -1.45397186478e-01f, 6.10668182370e-01f, 6.10668182370e-01f, -1.45397186478e-01f,
   4.3619155884e-02f, -1.0385513306e-02f,  1.615524292e-03f, -1.20162964e-04f
};

__device__ __forceinline__ int clampi(int v) { return v < 0 ? 0 : (v > HH - 1 ? HH - 1 : v); }

__device__ __forceinline__ int swzc(int c, int r) {
  return c ^ ((c >> 3) & 1) ^ ((r >> 2) & 3);
}

__device__ __forceinline__ half2v mk2(_Float16 a, _Float16 b) {
  half2v r; r.x = a; r.y = b; return r;
}

template<int J>
__device__ __forceinline__ half2v sel(half8v a, half8v b, half8v c, half8v d) {
  constexpr int V = J >> 2, E = J & 3;
  const half8v s = (V == 0) ? a : (V == 1) ? b : (V == 2) ? c : d;
  return mk2(s[2 * E], s[2 * E + 1]);
}
template<int E>
__device__ __forceinline__ half2v g2(half8v v) { return mk2(v[2 * E], v[2 * E + 1]); }

__device__ __forceinline__ float dot2acc(half2v w, half2v k, float acc) {
#if HAS_FDOT2
  return __builtin_amdgcn_fdot2(w, k, acc, false);
#else
  return acc + (float)w.x * (float)k.x + (float)w.y * (float)k.y;
#endif
}

// ======== shared macro definitions for the compute pipeline ========
#define STG(W0, W1, W2x, W3x, K0, K1, K2x, s) do {                       \
    const int r_ = rbase + (s);                                          \
    const _Float16* rp_ = tile + r_ * ROWH;                              \
    W0 = *(const half8v*)(rp_ + (swzc(2 * tx + 0, r_) << 3));            \
    W1 = *(const half8v*)(rp_ + (swzc(2 * tx + 1, r_) << 3));            \
    W2x = *(const half8v*)(rp_ + (swzc(2 * tx + 2, r_) << 3));           \
    W3x = *(const half8v*)(rp_ + (swzc(2 * tx + 3, r_) << 3));           \
    const _Float16* kp_ = (const _Float16*)(ckh + (s) * 16);             \
    K0 = *(const half8v*)(kp_);                                          \
    K1 = *(const half8v*)(kp_ + 8);                                      \
    K2x = *(const half4v*)(kp_ + 16);                                    \
  } while (0)

#define ROWK(o, W0, W1, W2x, W3x, K0, K1, K2x, A, B)                     \
    A = dot2acc(sel<(o) + 0>(W0, W1, W2x, W3x), g2<0>(K0), A);           \
    B = dot2acc(sel<(o) + 1>(W0, W1, W2x, W3x), g2<1>(K0), B);           \
    A = dot2acc(sel<(o) + 2>(W0, W1, W2x, W3x), g2<2>(K0), A);           \
    B = dot2acc(sel<(o) + 3>(W0, W1, W2x, W3x), g2<3>(K0), B);           \
    A = dot2acc(sel<(o) + 4>(W0, W1, W2x, W3x), g2<0>(K1), A);           \
    B = dot2acc(sel<(o) + 5>(W0, W1, W2x, W3x), g2<1>(K1), B);           \
    A = dot2acc(sel<(o) + 6>(W0, W1, W2x, W3x), g2<2>(K1), A);           \
    B = dot2acc(sel<(o) + 7>(W0, W1, W2x, W3x), g2<3>(K1), B);           \
    A = dot2acc(sel<(o) + 8>(W0, W1, W2x, W3x), mk2(K2x[0], K2x[1]), A); \
    B = dot2acc(sel<(o) + 9>(W0, W1, W2x, W3x), mk2(K2x[2], K2x[3]), B);

#define STG_A(s) STG(wa0, wa1, wa2, wa3, ka0, ka1, ka2, s)
#define STG_B(s) STG(wb0, wb1, wb2, wb3, kb0, kb1, kb2, s)
#define COMP_A                                                           \
    ROWK(0, wa0, wa1, wa2, wa3, ka0, ka1, ka2, a0, b0)                   \
    ROWK(2, wa0, wa1, wa2, wa3, ka0, ka1, ka2, a1, b1)                   \
    ROWK(4, wa0, wa1, wa2, wa3, ka0, ka1, ka2, a2, b2)                   \
    ROWK(6, wa0, wa1, wa2, wa3, ka0, ka1, ka2, a3, b3)
#define COMP_B                                                           \
    ROWK(0, wb0, wb1, wb2, wb3, kb0, kb1, kb2, a0, b0)                   \
    ROWK(2, wb0, wb1, wb2, wb3, kb0, kb1, kb2, a1, b1)                   \
    ROWK(4, wb0, wb1, wb2, wb3, kb0, kb1, kb2, a2, b2)                   \
    ROWK(6, wb0, wb1, wb2, wb3, kb0, kb1, kb2, a3, b3)
#define PAIR(se) STG_B((se) + 1); COMP_A; STG_A((se) + 2); COMP_B;

#define PIPELINE_BODY                                                    \
  half8v wa0, wa1, wa2, wa3, wb0, wb1, wb2, wb3;                         \
  half8v ka0, ka1, kb0, kb1;                                             \
  half4v ka2, kb2;                                                       \
  float a0 = 0.f, a1 = 0.f, a2 = 0.f, a3 = 0.f;                          \
  float b0 = 0.f, b1 = 0.f, b2 = 0.f, b3 = 0.f;                          \
  STG_A(0);                                                              \
  PAIR(0)  PAIR(2)  PAIR(4)  PAIR(6)  PAIR(8)                            \
  PAIR(10) PAIR(12) PAIR(14) PAIR(16)                                    \
  STG_B(19); COMP_A; COMP_B;

#define TABLE_PREAMBLE                                                   \
  if (tid < 12)       avs[tid] = rf ? DEC12c[tid] : (tid == 6 ? 1.f : 0.f); \
  else if (tid < 24)  bvs[tid - 12] = cf ? DEC12c[tid - 12] : (tid - 12 == 6 ? 1.f : 0.f); \
  else if (tid < 105) { const int m = tid - 24; mlds[m] = mtfp[m * 8 + chC]; } \
  __syncthreads();                                                       \
  for (int i = tid; i < 180; i += NTHREADS) {                            \
    const int S = i / 9, v = i - S * 9;                                  \
    const int plo = (S - 8 > 0) ? S - 8 : 0, phi = (S < 11) ? S : 11;    \
    float s1 = 0.f;                                                      \
    for (int p = plo; p <= phi; ++p) s1 += avs[p] * mlds[(S - p) * 9 + v]; \
    kva[i] = s1;                                                         \
  }                                                                      \
  __syncthreads();                                                       \
  for (int i = tid; i < 200; i += NTHREADS) {                            \
    const int S = i / 10, m = i - S * 10;                                \
    float s[2];                                                          \
    _Pragma("unroll")                                                    \
    for (int h = 0; h < 2; ++h) {                                        \
      const int T = 2 * m + h;                                           \
      const int qlo = (T - 8 > 0) ? T - 8 : 0, qhi = (T < 11) ? T : 11;  \
      float acc = 0.f;                                                   \
      for (int q = qlo; q <= qhi; ++q) acc += bvs[q] * kva[S * 9 + (T - q)]; \
      s[h] = acc;                                                        \
    }                                                                    \
    ckh[S * 16 + m] = mk2((_Float16)s[0], (_Float16)s[1]);               \
  }

#define STAGE_TILE                                                       \
  for (int idx = tid; idx < NR * NCH; idx += NTHREADS) {                 \
    const int rr = idx / NCH, g = idx - rr * NCH;                        \
    const float* grow = src + (clampi(R0 + rr) << 10);                   \
    const int c0 = C0 + 8 * g;                                           \
    float v[8];                                                          \
    if (c0 >= 0 && c0 + 7 <= HH - 1) {                                   \
      __builtin_memcpy(v, grow + c0, 32);                                \
    } else {                                                             \
      _Pragma("unroll")                                                  \
      for (int i = 0; i < 8; ++i) v[i] = grow[clampi(c0 + i)];           \
    }                                                                    \
    _Float16 h[8];                                                       \
    _Pragma("unroll")                                                    \
    for (int i = 0; i < 8; ++i) h[i] = (_Float16)v[i];                   \
    __builtin_memcpy(tile + rr * ROWH + (swzc(g, rr) << 3), h, 16);      \
  }

// ---------------- main kernel (r9 structure, unchanged) ----------------
__global__ __launch_bounds__(NTHREADS, 3) void dgp_main(
    const float* __restrict__ inp, const float* __restrict__ mtfp,
    const int* __restrict__ rp, const int* __restrict__ cp,
    float* __restrict__ outg) {
  __shared__ __align__(64) _Float16 tile[NR * ROWH];   // 46080 B
  __shared__ __align__(64) half2v ckh[20 * 16];
  __shared__ float kva[180];
  __shared__ float mlds[81];
  __shared__ float avs[12], bvs[12];

  const int tid = threadIdx.x;
  const int bxt = blockIdx.x, by = blockIdx.y, bz = blockIdx.z;
  const int chC = bz & 7;
  const int rv = rp[bz], cv = cp[bz];
  const int ri = rv >> 1, rf = rv & 1, ci = cv >> 1, cf = cv & 1;
  const int Ri0 = 2 + 4 * TH * by - ri;
  const int Cj0 = 2 + 4 * TW * bxt - ci;
  const int R0 = Ri0 - 10, C0 = Cj0 - 10;

  TABLE_PREAMBLE
  const float* src = inp + ((size_t)bz << 20);
  STAGE_TILE
  __syncthreads();

  const int ty = tid >> 4;   // 0..15
  const int tx = tid & 15;   // 0..15
  const int rbase = 4 * ty;

  PIPELINE_BODY

  const int oi = TH * by + ty;
  float* orow = outg + ((size_t)bz * OHW + oi) * OHW + TW * bxt + 4 * tx;
  orow[0] = a0 + b0;
  orow[1] = a1 + b1;
  orow[2] = a2 + b2;
  orow[3] = a3 + b3;
}

// ---------------- probe 1: tables + staging only ----------------
__global__ __launch_bounds__(NTHREADS, 3) void dgp_probe_stage(
    const float* __restrict__ inp, const float* __restrict__ mtfp,
    const int* __restrict__ rp, const int* __restrict__ cp,
    float* __restrict__ wsf, int nwsf) {
  __shared__ __align__(64) _Float16 tile[NR * ROWH];
  __shared__ __align__(64) half2v ckh[20 * 16];
  __shared__ float kva[180];
  __shared__ float mlds[81];
  __shared__ float avs[12], bvs[12];

  const int tid = threadIdx.x;
  const int bxt = blockIdx.x, by = blockIdx.y, bz = blockIdx.z;
  const int chC = bz & 7;
  const int rv = rp[bz], cv = cp[bz];
  const int ri = rv >> 1, rf = rv & 1, ci = cv >> 1, cf = cv & 1;
  const int Ri0 = 2 + 4 * TH * by - ri;
  const int Cj0 = 2 + 4 * TW * bxt - ci;
  const int R0 = Ri0 - 10, C0 = Cj0 - 10;

  TABLE_PREAMBLE
  const float* src = inp + ((size_t)bz << 20);
  STAGE_TILE
  __syncthreads();

  // dynamic-index checksum read: keeps all staging writes live (rule #17)
  float s = 0.f;
  #pragma unroll
  for (int k = 0; k < 4; ++k) {
    const half8v v = *(const half8v*)(tile + tid * 8 + k * 5120);
    s += (float)v[0] + (float)v[3] + (float)v[7];
  }
  s += (float)ckh[tid & 255][0];
  const int bl = (bz * 16 + by) * 4 + bxt;
  const int idx = bl * NTHREADS + tid;
  if (idx < nwsf) wsf[idx] = s;
}

// ---------------- probe 2: tables + synthetic fill + full compute ----------------
__global__ __launch_bounds__(NTHREADS, 3) void dgp_probe_comp(
    const float* __restrict__ inp, const float* __restrict__ mtfp,
    const int* __restrict__ rp, const int* __restrict__ cp,
    float* __restrict__ wsf, int nwsf) {
  __shared__ __align__(64) _Float16 tile[NR * ROWH];
  __shared__ __align__(64) half2v ckh[20 * 16];
  __shared__ float kva[180];
  __shared__ float mlds[81];
  __shared__ float avs[12], bvs[12];

  const int tid = threadIdx.x;
  const int bxt = blockIdx.x, by = blockIdx.y, bz = blockIdx.z;
  const int chC = bz & 7;
  const int rv = rp[bz], cv = cp[bz];
  const int ri = rv >> 1, rf = rv & 1, ci = cv >> 1, cf = cv & 1;
  (void)bxt; (void)by;

  TABLE_PREAMBLE

  // synthetic tile fill: no global loads, same LDS write volume as staging
  half8v fillv;
  #pragma unroll
  for (int j = 0; j < 8; ++j) fillv[j] = (_Float16)(0.01f * (float)(j + 1));
  for (int i = tid * 8; i < NR * ROWH; i += NTHREADS * 8)
    *(half8v*)(tile + i) = fillv;
  __syncthreads();

  const int ty = tid >> 4;
  const int tx = tid & 15;
  const int rbase = 4 * ty;

  PIPELINE_BODY

  const float s = a0 + a1 + a2 + a3 + b0 + b1 + b2 + b3;
  const int bl = (bz * 16 + by) * 4 + bxt;
  const int idx = bl * NTHREADS + tid;
  if (idx < nwsf) wsf[idx] = s;
}

#undef STG
#undef ROWK
#undef STG_A
#undef STG_B
#undef COMP_A
#undef COMP_B
#undef PAIR
#undef PIPELINE_BODY
#undef TABLE_PREAMBLE
#undef STAGE_TILE

// ---------------- edge fixup: masked-separable recompute of rows/cols {0,1,255} ----------------
__global__ __launch_bounds__(128) void dgp_edgefix(
    const float* __restrict__ inp, const float* __restrict__ mtfp,
    const int* __restrict__ rp, const int* __restrict__ cp,
    float* __restrict__ outg) {
  __shared__ __align__(16) float tile[20 * ESPAN];
  __shared__ __align__(16) float ck[400];
  __shared__ float kva[180];
  __shared__ float mlds[81];
  __shared__ float avs[12], bvs[12];

  const int tid = threadIdx.x;
  const int bx = blockIdx.x, by = blockIdx.y, bz = blockIdx.z;
  const bool isRow = (by < 3);
  const int segi = isRow ? by : by - 3;
  const int fixedo = (segi == 2) ? 255 : segi;
  const int chC = bz & 7;
  const int rv = rp[bz], cv = cp[bz];
  const int ri = rv >> 1, rf = rv & 1, ci = cv >> 1, cf = cv & 1;

  if (tid < 12) {
    float av = rf ? DEC12c[tid] : (tid == 6 ? 1.f : 0.f);
    if (isRow) {
      const int xi = (2 + 4 * fixedo - ri) - 6 + tid;
      if (xi < 0 || xi >= HH) av = 0.f;
    }
    avs[tid] = av;
  } else if (tid < 24) {
    const int q = tid - 12;
    float bv = cf ? DEC12c[q] : (q == 6 ? 1.f : 0.f);
    if (!isRow) {
      const int xj = (2 + 4 * fixedo - ci) - 6 + q;
      if (xj < 0 || xj >= HH) bv = 0.f;
    }
    bvs[q] = bv;
  } else if (tid < 105) {
    const int m = tid - 24; mlds[m] = mtfp[m * 8 + chC];
  }
  __syncthreads();

  for (int i = tid; i < 180; i += 128) {
    const int S = i / 9, v = i - S * 9;
    const int plo = (S - 8 > 0) ? S - 8 : 0, phi = (S < 11) ? S : 11;
    float s1 = 0.f;
    for (int p = plo; p <= phi; ++p) s1 += avs[p] * mlds[(S - p) * 9 + v];
    kva[i] = s1;
  }
  __syncthreads();
  for (int i = tid; i < 400; i += 128) {
    const int S = i / 20, T = i - S * 20;
    const int qlo = (T - 8 > 0) ? T - 8 : 0, qhi = (T < 11) ? T : 11;
    float s1 = 0.f;
    for (int q = qlo; q <= qhi; ++q) s1 += bvs[q] * kva[S * 9 + (T - q)];
    ck[i] = s1;
  }

  const float* src = inp + ((size_t)bz << 20);
  if (isRow) {
    const int R0 = (2 + 4 * fixedo - ri) - 10;
    const int C0c = 512 * bx - 8 - ci;
    for (int i = tid; i < 20 * ECHUNK; i += 128) {
      const int rr = i / ECHUNK, jc = i - rr * ECHUNK;
      const float* grow = src + (clampi(R0 + rr) << 10);
      const int c0 = C0c + 4 * jc;
      float4 v;
      v.x = grow[clampi(c0 + 0)];
      v.y = grow[clampi(c0 + 1)];
      v.z = grow[clampi(c0 + 2)];
      v.w = grow[clampi(c0 + 3)];
      *(float4*)(tile + rr * ESPAN + 4 * jc) = v;
    }
  } else {
    const int Cw0 = (2 + 4 * fixedo - ci) - 10;
    const int Rr0 = 512 * bx - 8 - ri;
    for (int i = tid; i < 20 * ESPAN; i += 128) {
      const int T = i / ESPAN, rr = i - T * ESPAN;
      tile[T * ESPAN + rr] = src[(clampi(Rr0 + rr) << 10) + clampi(Cw0 + T)];
    }
  }
  __syncthreads();

  float acc = 0.f;
  #pragma unroll 4
  for (int L = 0; L < 20; ++L) {
    const float* wp = tile + L * ESPAN + 4 * tid;
    float w[20];
    #pragma unroll
    for (int j = 0; j < 5; ++j) {
      const float4 v = *(const float4*)(wp + 4 * j);
      w[4 * j] = v.x; w[4 * j + 1] = v.y; w[4 * j + 2] = v.z; w[4 * j + 3] = v.w;
    }
    if (isRow) {
      #pragma unroll
      for (int e = 0; e < 20; ++e) acc += ck[L * 20 + e] * w[e];
    } else {
      #pragma unroll
      for (int e = 0; e < 20; ++e) acc += ck[e * 20 + L] * w[e];
    }
  }

  int oi, oj;
  if (isRow) { oi = fixedo; oj = 128 * bx + tid; }
  else       { oj = fixedo; oi = 128 * bx + tid; }
  outg[((size_t)bz * OHW + oi) * OHW + oj] = acc;
}

// ---------------- corner fixup ----------------
__global__ __launch_bounds__(64) void dgp_cornerfix(
    const float* __restrict__ inp, const float* __restrict__ mtfp,
    const int* __restrict__ rp, const int* __restrict__ cp,
    float* __restrict__ outg) {
  __shared__ float mlds[81];
  __shared__ float avs[12], bvs[12];
  const int lane = threadIdx.x;
  const int bi = blockIdx.x, bj = blockIdx.y, bz = blockIdx.z;
  const int oi = (bi == 2) ? 255 : bi;
  const int oj = (bj == 2) ? 255 : bj;
  const int chC = bz & 7;
  const int rv = rp[bz], cv = cp[bz];
  const int ri = rv >> 1, rf = rv & 1, ci = cv >> 1, cf = cv & 1;

  if (lane < 12)       avs[lane] = rf ? DEC12c[lane] : (lane == 6 ? 1.f : 0.f);
  else if (lane < 24)  bvs[lane - 12] = cf ? DEC12c[lane - 12] : (lane - 12 == 6 ? 1.f : 0.f);
  for (int m = lane; m < 81; m += 64) mlds[m] = mtfp[m * 8 + chC];
  __syncthreads();

  const int Ri = 2 + 4 * oi - ri;
  const int Cj = 2 + 4 * oj - ci;
  const float* src = inp + ((size_t)bz << 20);

  float acc = 0.f;
  for (int pair = lane; pair < 144; pair += 64) {
    const int p = pair / 12, q = pair - 12 * (pair / 12);
    const int xi = Ri - 6 + p, xj = Cj - 6 + q;
    if (xi < 0 || xi >= HH || xj < 0 || xj >= HH) continue;
    const float ab = avs[p] * bvs[q];
    if (ab == 0.f) continue;
    float s = 0.f;
    #pragma unroll
    for (int u = 0; u < 9; ++u) {
      const float* grow = src + (clampi(xi - 4 + u) << 10);
      #pragma unroll
      for (int v = 0; v < 9; ++v) s += mlds[u * 9 + v] * grow[clampi(xj - 4 + v)];
    }
    acc += ab * s;
  }
  #pragma unroll
  for (int off = 32; off > 0; off >>= 1) acc += __shfl_down(acc, off);
  if (lane == 0) outg[((size_t)bz * OHW + oi) * OHW + oj] = acc;
}

extern "C" void kernel_launch(void* const* d_in, const int* in_sizes, int n_in,
                              void* d_out, int out_size, void* d_ws, size_t ws_size,
                              hipStream_t stream) {
  const float* inp  = (const float*)d_in[0];
  const float* mtfp = (const float*)d_in[1];
  const int*   rp   = (const int*)d_in[2];
  const int*   cp   = (const int*)d_in[3];
  float* outg = (float*)d_out;
  float* wsf = (float*)d_ws;
  const int nwsf = (int)(ws_size / 4);

  hipLaunchKernelGGL(dgp_main, dim3(OHW / TW, OHW / TH, 32), dim3(NTHREADS), 0, stream,
                     inp, mtfp, rp, cp, outg);
  hipLaunchKernelGGL(dgp_edgefix, dim3(2, 6, 32), dim3(128), 0, stream,
                     inp, mtfp, rp, cp, outg);
  hipLaunchKernelGGL(dgp_cornerfix, dim3(3, 3, 32), dim3(64), 0, stream,
                     inp, mtfp, rp, cp, outg);
  // ---- measurement probes (write only to d_ws; per-dispatch dur_us in rocprof) ----
  hipLaunchKernelGGL(dgp_probe_stage, dim3(OHW / TW, OHW / TH, 32), dim3(NTHREADS), 0, stream,
                     inp, mtfp, rp, cp, wsf, nwsf);
  hipLaunchKernelGGL(dgp_probe_comp, dim3(OHW / TW, OHW / TH, 32), dim3(NTHREADS), 0, stream,
                     inp, mtfp, rp, cp, wsf, nwsf);
}

// Round 12
// 139.266 us; speedup vs baseline: 2.0065x; 2.0065x over previous
//
#include <hip/hip_runtime.h>

typedef _Float16 half2v __attribute__((ext_vector_type(2)));
typedef _Float16 half4v __attribute__((ext_vector_type(4)));
typedef _Float16 half8v __attribute__((ext_vector_type(8)));

#define HH 1024
#define OHW 256
#define TH 16
#define TW 32
#define NR 80        // input-tile rows
#define NCH 18       // data chunks (8 halves) per row = 144 cols
#define ROWH 160     // padded row stride in halves (20 chunks)
#define NTHREADS 256
#define ESPAN 528
#define ECHUNK (ESPAN/4)

#if defined(__has_builtin)
#  if __has_builtin(__builtin_amdgcn_fdot2)
#    define HAS_FDOT2 1
#  endif
#endif
#ifndef HAS_FDOT2
#  define HAS_FDOT2 0
#endif

__constant__ float DEC12c[12] = {
  -1.20162964e-04f,  1.615524292e-03f, -1.0385513306e-02f,  4.3619155884e-02f,
  -1.45397186478e-01f, 6.10668182370e-01f, 6.10668182370e-01f, -1.45397186478e-01f,
   4.3619155884e-02f, -1.0385513306e-02f,  1.615524292e-03f, -1.20162964e-04f
};

__device__ __forceinline__ int clampi(int v) { return v < 0 ? 0 : (v > HH - 1 ? HH - 1 : v); }

__device__ __forceinline__ int swzc(int c, int r) {
  return c ^ ((c >> 3) & 1) ^ ((r >> 2) & 3);
}

__device__ __forceinline__ half2v mk2(_Float16 a, _Float16 b) {
  half2v r; r.x = a; r.y = b; return r;
}

template<int J>   // J = half2 index 0..11 within 3 half8 regs
__device__ __forceinline__ half2v sel3(half8v a, half8v b, half8v c) {
  constexpr int V = J >> 2, E = J & 3;
  const half8v s = (V == 0) ? a : (V == 1) ? b : c;
  return mk2(s[2 * E], s[2 * E + 1]);
}
template<int E>
__device__ __forceinline__ half2v g2(half8v v) { return mk2(v[2 * E], v[2 * E + 1]); }

__device__ __forceinline__ float dot2acc(half2v w, half2v k, float acc) {
#if HAS_FDOT2
  return __builtin_amdgcn_fdot2(w, k, acc, false);
#else
  return acc + (float)w.x * (float)k.x + (float)w.y * (float)k.y;
#endif
}

// ---------------- kernel builder: per-image combined 20x20 kernel -> d_ws (f16) ----------------
// layout: ckg half index = bz*640 + S*32 + 2m (+1);  S=0..19, m=0..9 half2s used
__global__ __launch_bounds__(128) void dgp_ckbuild(
    const float* __restrict__ mtfp, const int* __restrict__ rp,
    const int* __restrict__ cp, _Float16* __restrict__ ckg) {
  __shared__ float kva[180];
  __shared__ float mlds[81];
  __shared__ float avs[12], bvs[12];
  const int tid = threadIdx.x;
  const int bz = blockIdx.x;
  const int chC = bz & 7;
  const int rv = rp[bz], cv = cp[bz];
  const int rf = rv & 1, cf = cv & 1;

  if (tid < 12)       avs[tid] = rf ? DEC12c[tid] : (tid == 6 ? 1.f : 0.f);
  else if (tid < 24)  bvs[tid - 12] = cf ? DEC12c[tid - 12] : (tid - 12 == 6 ? 1.f : 0.f);
  else if (tid < 105) { const int m = tid - 24; mlds[m] = mtfp[m * 8 + chC]; }
  __syncthreads();

  for (int i = tid; i < 180; i += 128) {
    const int S = i / 9, v = i - S * 9;
    const int plo = (S - 8 > 0) ? S - 8 : 0, phi = (S < 11) ? S : 11;
    float s1 = 0.f;
    for (int p = plo; p <= phi; ++p) s1 += avs[p] * mlds[(S - p) * 9 + v];
    kva[i] = s1;
  }
  __syncthreads();

  half2v* out2 = (half2v*)ckg;
  for (int i = tid; i < 200; i += 128) {
    const int S = i / 10, m = i - S * 10;
    float s[2];
    #pragma unroll
    for (int h = 0; h < 2; ++h) {
      const int T = 2 * m + h;
      const int qlo = (T - 8 > 0) ? T - 8 : 0, qhi = (T < 11) ? T : 11;
      float acc = 0.f;
      for (int q = qlo; q <= qhi; ++q) acc += bvs[q] * kva[S * 9 + (T - q)];
      s[h] = acc;
    }
    out2[bz * 320 + S * 16 + m] = mk2((_Float16)s[0], (_Float16)s[1]);
  }
}

// ---------------- main kernel: 25.6 KB LDS tile, kernel rows via uniform global loads ----------------
__global__ __launch_bounds__(NTHREADS, 6) void dgp_main(
    const float* __restrict__ inp, const int* __restrict__ rp,
    const int* __restrict__ cp, const _Float16* __restrict__ ckg,
    float* __restrict__ outg) {
  __shared__ __align__(64) _Float16 tile[NR * ROWH];   // 25600 B

  const int tid = threadIdx.x;
  const int bxt = blockIdx.x, by = blockIdx.y, bz = blockIdx.z;
  const int rv = rp[bz], cv = cp[bz];
  const int ri = rv >> 1, ci = cv >> 1;
  const int R0 = 4 * TH * by - 8 - ri;     // (2 + 4*TH*by - ri) - 10
  const int C0 = 4 * TW * bxt - 8 - ci;

  // stage 80x144 tile as f16, swizzled chunks; per-chunk interior fast path
  const float* src = inp + ((size_t)bz << 20);
  for (int idx = tid; idx < NR * NCH; idx += NTHREADS) {
    const int rr = idx / NCH, g = idx - rr * NCH;
    const float* grow = src + (clampi(R0 + rr) << 10);
    const int c0 = C0 + 8 * g;
    float v[8];
    if (c0 >= 0 && c0 + 7 <= HH - 1) {
      __builtin_memcpy(v, grow + c0, 32);
    } else {
      #pragma unroll
      for (int i = 0; i < 8; ++i) v[i] = grow[clampi(c0 + i)];
    }
    _Float16 h[8];
    #pragma unroll
    for (int i = 0; i < 8; ++i) h[i] = (_Float16)v[i];
    __builtin_memcpy(tile + rr * ROWH + (swzc(g, rr) << 3), h, 16);
  }
  __syncthreads();

  const int ty = tid >> 4;   // 0..15 output row
  const int tx = tid & 15;   // 0..15 -> 2 outputs at cols 2tx, 2tx+1
  const int rbase = 4 * ty;
  const size_t kbase = (size_t)bz * 640;

  float a0e = 0.f, a0o = 0.f, a1e = 0.f, a1o = 0.f;

#define DOT_STEP(s_) do {                                                \
    const int r_ = rbase + (s_);                                         \
    const _Float16* rp_ = tile + r_ * ROWH;                              \
    const half8v w0 = *(const half8v*)(rp_ + (swzc(tx + 0, r_) << 3));   \
    const half8v w1 = *(const half8v*)(rp_ + (swzc(tx + 1, r_) << 3));   \
    const half8v w2 = *(const half8v*)(rp_ + (swzc(tx + 2, r_) << 3));   \
    const _Float16* kp_ = ckg + kbase + (s_) * 32;                       \
    const half8v K0 = *(const half8v*)(kp_);                             \
    const half8v K1 = *(const half8v*)(kp_ + 8);                         \
    const half4v K2 = *(const half4v*)(kp_ + 16);                        \
    a0e = dot2acc(sel3<0>(w0, w1, w2), g2<0>(K0), a0e);                  \
    a0o = dot2acc(sel3<1>(w0, w1, w2), g2<1>(K0), a0o);                  \
    a0e = dot2acc(sel3<2>(w0, w1, w2), g2<2>(K0), a0e);                  \
    a0o = dot2acc(sel3<3>(w0, w1, w2), g2<3>(K0), a0o);                  \
    a0e = dot2acc(sel3<4>(w0, w1, w2), g2<0>(K1), a0e);                  \
    a0o = dot2acc(sel3<5>(w0, w1, w2), g2<1>(K1), a0o);                  \
    a0e = dot2acc(sel3<6>(w0, w1, w2), g2<2>(K1), a0e);                  \
    a0o = dot2acc(sel3<7>(w0, w1, w2), g2<3>(K1), a0o);                  \
    a0e = dot2acc(sel3<8>(w0, w1, w2), mk2(K2[0], K2[1]), a0e);          \
    a0o = dot2acc(sel3<9>(w0, w1, w2), mk2(K2[2], K2[3]), a0o);          \
    a1e = dot2acc(sel3<2>(w0, w1, w2), g2<0>(K0), a1e);                  \
    a1o = dot2acc(sel3<3>(w0, w1, w2), g2<1>(K0), a1o);                  \
    a1e = dot2acc(sel3<4>(w0, w1, w2), g2<2>(K0), a1e);                  \
    a1o = dot2acc(sel3<5>(w0, w1, w2), g2<3>(K0), a1o);                  \
    a1e = dot2acc(sel3<6>(w0, w1, w2), g2<0>(K1), a1e);                  \
    a1o = dot2acc(sel3<7>(w0, w1, w2), g2<1>(K1), a1o);                  \
    a1e = dot2acc(sel3<8>(w0, w1, w2), g2<2>(K1), a1e);                  \
    a1o = dot2acc(sel3<9>(w0, w1, w2), g2<3>(K1), a1o);                  \
    a1e = dot2acc(sel3<10>(w0, w1, w2), mk2(K2[0], K2[1]), a1e);         \
    a1o = dot2acc(sel3<11>(w0, w1, w2), mk2(K2[2], K2[3]), a1o);         \
  } while (0)

  DOT_STEP(0);  DOT_STEP(1);  DOT_STEP(2);  DOT_STEP(3);  DOT_STEP(4);
  DOT_STEP(5);  DOT_STEP(6);  DOT_STEP(7);  DOT_STEP(8);  DOT_STEP(9);
  DOT_STEP(10); DOT_STEP(11); DOT_STEP(12); DOT_STEP(13); DOT_STEP(14);
  DOT_STEP(15); DOT_STEP(16); DOT_STEP(17); DOT_STEP(18); DOT_STEP(19);
#undef DOT_STEP

  const int oi = TH * by + ty;
  float2 o2;
  o2.x = a0e + a0o;
  o2.y = a1e + a1o;
  *(float2*)(outg + ((size_t)bz * OHW + oi) * OHW + TW * bxt + 2 * tx) = o2;
}

// ---------------- edge fixup: masked-separable recompute of rows/cols {0,1,255} ----------------
__global__ __launch_bounds__(128) void dgp_edgefix(
    const float* __restrict__ inp, const float* __restrict__ mtfp,
    const int* __restrict__ rp, const int* __restrict__ cp,
    float* __restrict__ outg) {
  __shared__ __align__(16) float tile[20 * ESPAN];
  __shared__ __align__(16) float ck[400];
  __shared__ float kva[180];
  __shared__ float mlds[81];
  __shared__ float avs[12], bvs[12];

  const int tid = threadIdx.x;
  const int bx = blockIdx.x, by = blockIdx.y, bz = blockIdx.z;
  const bool isRow = (by < 3);
  const int segi = isRow ? by : by - 3;
  const int fixedo = (segi == 2) ? 255 : segi;
  const int chC = bz & 7;
  const int rv = rp[bz], cv = cp[bz];
  const int ri = rv >> 1, rf = rv & 1, ci = cv >> 1, cf = cv & 1;

  if (tid < 12) {
    float av = rf ? DEC12c[tid] : (tid == 6 ? 1.f : 0.f);
    if (isRow) {
      const int xi = (2 + 4 * fixedo - ri) - 6 + tid;
      if (xi < 0 || xi >= HH) av = 0.f;
    }
    avs[tid] = av;
  } else if (tid < 24) {
    const int q = tid - 12;
    float bv = cf ? DEC12c[q] : (q == 6 ? 1.f : 0.f);
    if (!isRow) {
      const int xj = (2 + 4 * fixedo - ci) - 6 + q;
      if (xj < 0 || xj >= HH) bv = 0.f;
    }
    bvs[q] = bv;
  } else if (tid < 105) {
    const int m = tid - 24; mlds[m] = mtfp[m * 8 + chC];
  }
  __syncthreads();

  for (int i = tid; i < 180; i += 128) {
    const int S = i / 9, v = i - S * 9;
    const int plo = (S - 8 > 0) ? S - 8 : 0, phi = (S < 11) ? S : 11;
    float s1 = 0.f;
    for (int p = plo; p <= phi; ++p) s1 += avs[p] * mlds[(S - p) * 9 + v];
    kva[i] = s1;
  }
  __syncthreads();
  for (int i = tid; i < 400; i += 128) {
    const int S = i / 20, T = i - S * 20;
    const int qlo = (T - 8 > 0) ? T - 8 : 0, qhi = (T < 11) ? T : 11;
    float s1 = 0.f;
    for (int q = qlo; q <= qhi; ++q) s1 += bvs[q] * kva[S * 9 + (T - q)];
    ck[i] = s1;
  }

  const float* src = inp + ((size_t)bz << 20);
  if (isRow) {
    const int R0 = (2 + 4 * fixedo - ri) - 10;
    const int C0c = 512 * bx - 8 - ci;
    for (int i = tid; i < 20 * ECHUNK; i += 128) {
      const int rr = i / ECHUNK, jc = i - rr * ECHUNK;
      const float* grow = src + (clampi(R0 + rr) << 10);
      const int c0 = C0c + 4 * jc;
      float4 v;
      v.x = grow[clampi(c0 + 0)];
      v.y = grow[clampi(c0 + 1)];
      v.z = grow[clampi(c0 + 2)];
      v.w = grow[clampi(c0 + 3)];
      *(float4*)(tile + rr * ESPAN + 4 * jc) = v;
    }
  } else {
    const int Cw0 = (2 + 4 * fixedo - ci) - 10;
    const int Rr0 = 512 * bx - 8 - ri;
    for (int i = tid; i < 20 * ESPAN; i += 128) {
      const int T = i / ESPAN, rr = i - T * ESPAN;
      tile[T * ESPAN + rr] = src[(clampi(Rr0 + rr) << 10) + clampi(Cw0 + T)];
    }
  }
  __syncthreads();

  float acc = 0.f;
  #pragma unroll 4
  for (int L = 0; L < 20; ++L) {
    const float* wp = tile + L * ESPAN + 4 * tid;
    float w[20];
    #pragma unroll
    for (int j = 0; j < 5; ++j) {
      const float4 v = *(const float4*)(wp + 4 * j);
      w[4 * j] = v.x; w[4 * j + 1] = v.y; w[4 * j + 2] = v.z; w[4 * j + 3] = v.w;
    }
    if (isRow) {
      #pragma unroll
      for (int e = 0; e < 20; ++e) acc += ck[L * 20 + e] * w[e];
    } else {
      #pragma unroll
      for (int e = 0; e < 20; ++e) acc += ck[e * 20 + L] * w[e];
    }
  }

  int oi, oj;
  if (isRow) { oi = fixedo; oj = 128 * bx + tid; }
  else       { oj = fixedo; oi = 128 * bx + tid; }
  outg[((size_t)bz * OHW + oi) * OHW + oj] = acc;
}

// ---------------- corner fixup ----------------
__global__ __launch_bounds__(64) void dgp_cornerfix(
    const float* __restrict__ inp, const float* __restrict__ mtfp,
    const int* __restrict__ rp, const int* __restrict__ cp,
    float* __restrict__ outg) {
  __shared__ float mlds[81];
  __shared__ float avs[12], bvs[12];
  const int lane = threadIdx.x;
  const int bi = blockIdx.x, bj = blockIdx.y, bz = blockIdx.z;
  const int oi = (bi == 2) ? 255 : bi;
  const int oj = (bj == 2) ? 255 : bj;
  const int chC = bz & 7;
  const int rv = rp[bz], cv = cp[bz];
  const int ri = rv >> 1, rf = rv & 1, ci = cv >> 1, cf = cv & 1;

  if (lane < 12)       avs[lane] = rf ? DEC12c[lane] : (lane == 6 ? 1.f : 0.f);
  else if (lane < 24)  bvs[lane - 12] = cf ? DEC12c[lane - 12] : (lane - 12 == 6 ? 1.f : 0.f);
  for (int m = lane; m < 81; m += 64) mlds[m] = mtfp[m * 8 + chC];
  __syncthreads();

  const int Ri = 2 + 4 * oi - ri;
  const int Cj = 2 + 4 * oj - ci;
  const float* src = inp + ((size_t)bz << 20);

  float acc = 0.f;
  for (int pair = lane; pair < 144; pair += 64) {
    const int p = pair / 12, q = pair - 12 * (pair / 12);
    const int xi = Ri - 6 + p, xj = Cj - 6 + q;
    if (xi < 0 || xi >= HH || xj < 0 || xj >= HH) continue;
    const float ab = avs[p] * bvs[q];
    if (ab == 0.f) continue;
    float s = 0.f;
    #pragma unroll
    for (int u = 0; u < 9; ++u) {
      const float* grow = src + (clampi(xi - 4 + u) << 10);
      #pragma unroll
      for (int v = 0; v < 9; ++v) s += mlds[u * 9 + v] * grow[clampi(xj - 4 + v)];
    }
    acc += ab * s;
  }
  #pragma unroll
  for (int off = 32; off > 0; off >>= 1) acc += __shfl_down(acc, off);
  if (lane == 0) outg[((size_t)bz * OHW + oi) * OHW + oj] = acc;
}

extern "C" void kernel_launch(void* const* d_in, const int* in_sizes, int n_in,
                              void* d_out, int out_size, void* d_ws, size_t ws_size,
                              hipStream_t stream) {
  const float* inp  = (const float*)d_in[0];
  const float* mtfp = (const float*)d_in[1];
  const int*   rp   = (const int*)d_in[2];
  const int*   cp   = (const int*)d_in[3];
  float* outg = (float*)d_out;
  _Float16* ckg = (_Float16*)d_ws;   // 32 * 640 halves = 40 KB

  hipLaunchKernelGGL(dgp_ckbuild, dim3(32), dim3(128), 0, stream, mtfp, rp, cp, ckg);
  hipLaunchKernelGGL(dgp_main, dim3(OHW / TW, OHW / TH, 32), dim3(NTHREADS), 0, stream,
                     inp, rp, cp, (const _Float16*)ckg, outg);
  hipLaunchKernelGGL(dgp_edgefix, dim3(2, 6, 32), dim3(128), 0, stream,
                     inp, mtfp, rp, cp, outg);
  hipLaunchKernelGGL(dgp_cornerfix, dim3(3, 3, 32), dim3(64), 0, stream,
                     inp, mtfp, rp, cp, outg);
}